// Round 18
// baseline (274.556 us; speedup 1.0000x reference)
//
#include <hip/hip_runtime.h>
#include <stdint.h>

// Problem constants: B=4, S=2048, D=1024, H=8, DK=128, C=128
typedef __attribute__((ext_vector_type(8))) short short8;
typedef __attribute__((ext_vector_type(4))) float floatx4;

#if defined(__has_builtin)
#if __has_builtin(__builtin_amdgcn_exp2f)
#define EXP2(x) __builtin_amdgcn_exp2f(x)
#endif
#endif
#ifndef EXP2
#define EXP2(x) exp2f(x)
#endif

// sign-extend bit `off` of x to a full 32-bit mask (v_bfe_i32)
#if defined(__has_builtin)
#if __has_builtin(__builtin_amdgcn_sbfe)
#define SBFE1(x, off) __builtin_amdgcn_sbfe((int)(x), (off), 1)
#endif
#endif
#ifndef SBFE1
#define SBFE1(x, off) (((int)((uint32_t)(x) << (31 - (off)))) >> 31)
#endif
// -192.0f bit pattern: masked logits get exp2(acc-192) -> flushed to 0
#define MBIAS_BITS 0xC3400000

__device__ __forceinline__ float mask_bias(uint32_t wlo, int off) {
  int ms = SBFE1(wlo, off);
  union { int i; float f; } u; u.i = ms & (int)MBIAS_BITS;
  return u.f;
}

// 1/sqrt(128) * log2(e)  — folded into W_q so softmax needs only v_exp_f32
#define WQ_SCALE (0.08838834764831845f * 1.4426950408889634f)

// counted waits + raw barrier (T4): never drain vmcnt to 0 in the main loop
#define VMCNT_(n) asm volatile("s_waitcnt vmcnt(" #n ")" ::: "memory")
#define SBAR() do { asm volatile("" ::: "memory"); __builtin_amdgcn_s_barrier(); \
                    asm volatile("" ::: "memory"); } while (0)

__device__ __forceinline__ unsigned short f2bf(float f) {
  union { float f; uint32_t u; } v; v.f = f;
  return (unsigned short)((v.u + 0x7fffu + ((v.u >> 16) & 1u)) >> 16);
}

// async global->LDS DMA, 16B per lane; dst is wave-uniform base (+lane*16 implicit)
__device__ __forceinline__ void gld_lds16(const void* g, void* l) {
  __builtin_amdgcn_global_load_lds((const __attribute__((address_space(1))) uint32_t*)g,
                                   (__attribute__((address_space(3))) uint32_t*)l, 16, 0, 0);
}

// ---- fused prep: blocks 0..8191 cvt x; 8192..16383 cvt W_q/W_k --------------
// block 0 additionally detects mask element width (int32 vs uint8)
__global__ void k_prep(const float4* __restrict__ x, uint2* __restrict__ xbf,
                       const float* __restrict__ wq, const float* __restrict__ wk,
                       unsigned short* __restrict__ wqkt,
                       const uint32_t* __restrict__ m, int* __restrict__ flag) {
  if (blockIdx.x < 8192) {
    long i = (long)blockIdx.x * 256 + threadIdx.x;
    float4 v = x[i];
    uint2 o;
    o.x = (uint32_t)f2bf(v.x) | ((uint32_t)f2bf(v.y) << 16);
    o.y = (uint32_t)f2bf(v.z) | ((uint32_t)f2bf(v.w) << 16);
    xbf[i] = o;
    if (blockIdx.x == 0) {     // block-uniform branch: __syncthreads is legal
      __shared__ int any;
      if (threadIdx.x == 0) any = 0;
      __syncthreads();
      int a = 0;
      for (int j = threadIdx.x; j < 16384; j += 256) a |= (m[j] > 1u) ? 1 : 0;
      if (a) atomicOr(&any, 1);
      __syncthreads();
      if (threadIdx.x == 0) *flag = any;   // 1 => bytes, 0 => int32
    }
  } else {
    int tid = (blockIdx.x - 8192) * 256 + threadIdx.x;   // n*1024 + d
    int n = tid >> 10, d = tid & 1023;
    int isq = (n < 1024);
    const float* src = isq ? wq : wk;
    int nn = n & 1023;
    int h = nn >> 7, dk = nn & 127;
    float v = src[h * 131072 + d * 128 + dk];
    wqkt[tid] = f2bf(isq ? v * WQ_SCALE : v);
  }
}

// ---- bit-pack mask, ballot-natural layout -----------------------------------
// bit for (row=b*2048+q, s): word row*32 + (s>>8)*4 + (s&3), bitpos (s&255)>>2
__global__ void k_bitpack(const void* __restrict__ mask, const int* __restrict__ flag,
                          unsigned long long* __restrict__ bits) {
  long tid = (long)blockIdx.x * 256 + threadIdx.x;   // each thread: 4 consecutive elems
  int f = *flag;
  int l = threadIdx.x & 63;
  int nib;
  if (f) {
    uchar4 v = ((const uchar4*)mask)[tid];
    nib = (v.x != 0) | ((v.y != 0) << 1) | ((v.z != 0) << 2) | ((v.w != 0) << 3);
  } else {
    int4 v = ((const int4*)mask)[tid];
    nib = (v.x != 0) | ((v.y != 0) << 1) | ((v.z != 0) << 2) | ((v.w != 0) << 3);
  }
  unsigned long long b0 = __ballot((nib & 1) != 0);
  unsigned long long b1 = __ballot((nib & 2) != 0);
  unsigned long long b2 = __ballot((nib & 4) != 0);
  unsigned long long b3 = __ballot((nib & 8) != 0);
  if (l < 4) {
    long wb = (tid * 4) & ~255L;        // wave-base element index
    long row = wb >> 11;                 // (b*2048+q)
    int a = (int)((wb >> 8) & 7);
    unsigned long long val = (l == 0) ? b0 : ((l == 1) ? b1 : ((l == 2) ? b2 : b3));
    bits[row * 32 + a * 4 + l] = val;
  }
}

// ---- GEMM 256x256 tile, proven 2-barrier counted-vmcnt schedule (R15 best) --
__launch_bounds__(512, 2)
__global__ void k_gemm256(const unsigned short* __restrict__ xbf,
                          const unsigned short* __restrict__ wqkt,
                          unsigned short* __restrict__ qk) {
  __shared__ uint4 lds[2][2048];   // 2 x 32KB: A subtiles 0..15, B 16..31
  int bid = blockIdx.x;
  bid = (bid & 7) * 32 + (bid >> 3);          // XCD-chunked swizzle (256 % 8 == 0)
  int m0 = (bid >> 3) * 256, n0 = (bid & 7) * 256;
  int t = threadIdx.x, w = t >> 6, l = t & 63;
  int lr = l & 15, lc = l >> 4;
  int wr = w >> 2, wc = w & 3;                // wave grid 2M x 4N
  floatx4 z = {0.f, 0.f, 0.f, 0.f};
  floatx4 acc[8][4];
#pragma unroll
  for (int ii = 0; ii < 8; ii++)
#pragma unroll
    for (int jj = 0; jj < 4; jj++) acc[ii][jj] = z;

  auto stage = [&](int buf, int k0) {
#pragma unroll
    for (int j = 0; j < 4; j++) {
      int sub = w * 4 + j;   // 0..31: A mi=sub (0..15), B ni=sub-16
      const unsigned short* src = (sub < 16)
        ? xbf + (long)(m0 + sub * 16 + lr) * 1024 + k0 + lc * 8
        : wqkt + (long)(n0 + (sub - 16) * 16 + lr) * 1024 + k0 + lc * 8;
      gld_lds16(src, &lds[buf][sub * 64]);
    }
  };

  stage(0, 0);
  VMCNT_(0);
  SBAR();
  int cur = 0;
  for (int kt = 0; kt < 32; ++kt) {
    if (kt < 31) { stage(cur ^ 1, (kt + 1) * 32); VMCNT_(4); } else { VMCNT_(0); }
    SBAR();
    const unsigned short* al = (const unsigned short*)lds[cur];
    const unsigned short* bl = al + 8192;   // B at byte 16384
    short8 B[4], A0[4], A1[4];
#pragma unroll
    for (int nf = 0; nf < 4; nf++) B[nf] = *(const short8*)(bl + (wc * 4 + nf) * 512 + l * 8);
#pragma unroll
    for (int mf = 0; mf < 4; mf++) A0[mf] = *(const short8*)(al + (wr * 8 + mf) * 512 + l * 8);
    __builtin_amdgcn_s_setprio(1);
#pragma unroll
    for (int mf = 0; mf < 4; mf++)
#pragma unroll
      for (int nf = 0; nf < 4; nf++)
        acc[mf][nf] = __builtin_amdgcn_mfma_f32_16x16x32_bf16(A0[mf], B[nf], acc[mf][nf], 0, 0, 0);
#pragma unroll
    for (int mf = 0; mf < 4; mf++) A1[mf] = *(const short8*)(al + (wr * 8 + 4 + mf) * 512 + l * 8);
#pragma unroll
    for (int mf = 0; mf < 4; mf++)
#pragma unroll
      for (int nf = 0; nf < 4; nf++)
        acc[4 + mf][nf] = __builtin_amdgcn_mfma_f32_16x16x32_bf16(A1[mf], B[nf], acc[4 + mf][nf], 0, 0, 0);
    __builtin_amdgcn_s_setprio(0);
    SBAR();
    cur ^= 1;
  }
#pragma unroll
  for (int mf = 0; mf < 8; mf++)
#pragma unroll
    for (int nf = 0; nf < 4; nf++)
#pragma unroll
      for (int i = 0; i < 4; i++) {
        int row = m0 + wr * 128 + mf * 16 + lc * 4 + i;
        int col = n0 + wc * 64 + nf * 16 + lr;
        qk[(long)row * 2048 + col] = f2bf(acc[mf][nf][i]);
      }
}

// ---- attn pass A: rowsum[h*4+b][q] += sum_s exp2(logit + maskbias) ----------
// 512 thr = 8 waves; q-tile 256 (wave owns 32 q), s-tile 512 in 8 steps of 64.
// Mask regs loaded one step EARLY (prologue / end of step 3) so their wait is
// covered by the counted VMCNT_(2) — no vmcnt(0) drain inside the loop.
__launch_bounds__(512, 4)
__global__ void k_attn_rs(const unsigned short* __restrict__ qk,
                          const unsigned long long* __restrict__ bits,
                          float* __restrict__ rowsum) {
  __shared__ uint4 k4[2][1024];                 // 2 x 16KB K tile (64 keys x 128 dk)
  int qt = blockIdx.x >> 2, st = blockIdx.x & 3;
  int b = blockIdx.y, h = blockIdx.z;
  int t = threadIdx.x, w = t >> 6, l = t & 63;
  int lr = l & 15, lc = l >> 4;
  int q0 = qt * 256, sbase = st * 512;
  const unsigned short* Q = qk + (long)b * 4194304 + h * 128;
  const unsigned short* K = qk + (long)b * 4194304 + 1024 + h * 128;
  const unsigned long long* browB = bits + ((long)b * 2048 + q0) * 32 + (sbase >> 8) * 4;

  short8 qf[2][4];
#pragma unroll
  for (int mf = 0; mf < 2; mf++)
#pragma unroll
    for (int ki = 0; ki < 4; ki++)
      qf[mf][ki] = *(const short8*)(Q + (long)(q0 + w * 32 + mf * 16 + lr) * 2048 + ki * 32 + lc * 8);

  auto stageK = [&](int buf, int s0g) {
#pragma unroll
    for (int j = 0; j < 2; j++) {
      int sub = w * 2 + j, si = sub >> 2, ki = sub & 3;
      gld_lds16(K + (long)(s0g + si * 16 + lr) * 2048 + ki * 32 + lc * 8, &k4[buf][sub * 64]);
    }
  };

  unsigned long long mwreg[8];
  auto loadMask = [&](int jhi) {
#pragma unroll
    for (int mf = 0; mf < 2; mf++)
#pragma unroll
      for (int i2 = 0; i2 < 4; i2++)
        mwreg[mf * 4 + i2] =
            browB[(long)(w * 32 + mf * 16 + lc * 4 + i2) * 32 + jhi * 4 + (lr & 3)];
  };

  loadMask(0);            // in flight; prologue drains vmcnt anyway
  stageK(0, sbase);
  VMCNT_(0);
  SBAR();

  floatx4 z = {0.f, 0.f, 0.f, 0.f};
  float lsum[2][4] = {{0,0,0,0},{0,0,0,0}};
  int cur = 0;
  for (int i = 0; i < 8; ++i) {
    int s0g = sbase + i * 64;
    if (i < 7) { stageK(cur ^ 1, s0g + 64); VMCNT_(2); } else { VMCNT_(0); }
    SBAR();
    const unsigned short* kl = (const unsigned short*)k4[cur];
    floatx4 acc[2][4];
#pragma unroll
    for (int ii = 0; ii < 2; ii++)
#pragma unroll
      for (int jj = 0; jj < 4; jj++) acc[ii][jj] = z;
    __builtin_amdgcn_s_setprio(1);
#pragma unroll
    for (int ki = 0; ki < 4; ki++) {
      short8 bb[4];
#pragma unroll
      for (int si = 0; si < 4; si++) bb[si] = *(const short8*)(kl + (si * 4 + ki) * 512 + l * 8);
#pragma unroll
      for (int mf = 0; mf < 2; mf++)
#pragma unroll
        for (int si = 0; si < 4; si++)
          acc[mf][si] = __builtin_amdgcn_mfma_f32_16x16x32_bf16(qf[mf][ki], bb[si], acc[mf][si], 0, 0, 0);
    }
    __builtin_amdgcn_s_setprio(0);
    int shb = (i & 3) * 16 + (lr >> 2);
#pragma unroll
    for (int mf = 0; mf < 2; mf++)
#pragma unroll
      for (int i2 = 0; i2 < 4; i2++) {
        uint32_t wlo = (uint32_t)(mwreg[mf * 4 + i2] >> shb);
        float p = 0.f;
#pragma unroll
        for (int si = 0; si < 4; si++)
          p += EXP2(acc[mf][si][i2] + mask_bias(wlo, 4 * si));
        lsum[mf][i2] += p;
      }
    if (i == 3) loadMask(1);   // after last use of jhi=0 regs; covered by next VMCNT_(2)
    SBAR();
    cur ^= 1;
  }
#pragma unroll
  for (int mf = 0; mf < 2; mf++)
#pragma unroll
    for (int i2 = 0; i2 < 4; i2++) {
      float v = lsum[mf][i2];
      v += __shfl_xor(v, 1); v += __shfl_xor(v, 2);
      v += __shfl_xor(v, 4); v += __shfl_xor(v, 8);
      if (lr == 0)
        atomicAdd(&rowsum[((h * 4 + b) << 11) + q0 + w * 32 + mf * 16 + lc * 4 + i2], v);
    }
}

// ---- attn pass B: abar[h*4+b][s] += sum_q exp2(logit+maskbias)*rinv_q -------
__launch_bounds__(512, 4)
__global__ void k_attn_cs(const unsigned short* __restrict__ qk,
                          const unsigned long long* __restrict__ bits,
                          const float* __restrict__ rowsum,
                          float* __restrict__ abar) {
  __shared__ uint4 k4[2][1024];
  __shared__ float colacc[512];
  int qt = blockIdx.x >> 2, st = blockIdx.x & 3;
  int b = blockIdx.y, h = blockIdx.z;
  int t = threadIdx.x, w = t >> 6, l = t & 63;
  int lr = l & 15, lc = l >> 4;
  int q0 = qt * 256, sbase = st * 512;
  const unsigned short* Q = qk + (long)b * 4194304 + h * 128;
  const unsigned short* K = qk + (long)b * 4194304 + 1024 + h * 128;
  const unsigned long long* browB = bits + ((long)b * 2048 + q0) * 32 + (sbase >> 8) * 4;
  float* abG = abar + ((h * 4 + b) << 11) + sbase;

  short8 qf[2][4];
#pragma unroll
  for (int mf = 0; mf < 2; mf++)
#pragma unroll
    for (int ki = 0; ki < 4; ki++)
      qf[mf][ki] = *(const short8*)(Q + (long)(q0 + w * 32 + mf * 16 + lr) * 2048 + ki * 32 + lc * 8);

  float rinv[2][4];
#pragma unroll
  for (int mf = 0; mf < 2; mf++)
#pragma unroll
    for (int i2 = 0; i2 < 4; i2++)
      rinv[mf][i2] = 1.f / (rowsum[((h * 4 + b) << 11) + q0 + w * 32 + mf * 16 + lc * 4 + i2] * 2048.f);

  auto stageK = [&](int buf, int s0g) {
#pragma unroll
    for (int j = 0; j < 2; j++) {
      int sub = w * 2 + j, si = sub >> 2, ki = sub & 3;
      gld_lds16(K + (long)(s0g + si * 16 + lr) * 2048 + ki * 32 + lc * 8, &k4[buf][sub * 64]);
    }
  };

  unsigned long long mwreg[8];
  auto loadMask = [&](int jhi) {
#pragma unroll
    for (int mf = 0; mf < 2; mf++)
#pragma unroll
      for (int i2 = 0; i2 < 4; i2++)
        mwreg[mf * 4 + i2] =
            browB[(long)(w * 32 + mf * 16 + lc * 4 + i2) * 32 + jhi * 4 + (lr & 3)];
  };

  loadMask(0);
  stageK(0, sbase);
  colacc[t < 512 ? t : 0] = 0.f;
  VMCNT_(0);
  SBAR();

  floatx4 z = {0.f, 0.f, 0.f, 0.f};
  int cur = 0;
  for (int i = 0; i < 8; ++i) {
    int s0g = sbase + i * 64;
    if (i < 7) { stageK(cur ^ 1, s0g + 64); VMCNT_(2); } else { VMCNT_(0); }
    SBAR();
    const unsigned short* kl = (const unsigned short*)k4[cur];
    floatx4 acc[2][4];
#pragma unroll
    for (int ii = 0; ii < 2; ii++)
#pragma unroll
      for (int jj = 0; jj < 4; jj++) acc[ii][jj] = z;
    __builtin_amdgcn_s_setprio(1);
#pragma unroll
    for (int ki = 0; ki < 4; ki++) {
      short8 bb[4];
#pragma unroll
      for (int si = 0; si < 4; si++) bb[si] = *(const short8*)(kl + (si * 4 + ki) * 512 + l * 8);
#pragma unroll
      for (int mf = 0; mf < 2; mf++)
#pragma unroll
        for (int si = 0; si < 4; si++)
          acc[mf][si] = __builtin_amdgcn_mfma_f32_16x16x32_bf16(qf[mf][ki], bb[si], acc[mf][si], 0, 0, 0);
    }
    __builtin_amdgcn_s_setprio(0);
    int shb = (i & 3) * 16 + (lr >> 2);
    float cp[4] = {0.f, 0.f, 0.f, 0.f};
#pragma unroll
    for (int mf = 0; mf < 2; mf++)
#pragma unroll
      for (int i2 = 0; i2 < 4; i2++) {
        uint32_t wlo = (uint32_t)(mwreg[mf * 4 + i2] >> shb);
        float ri = rinv[mf][i2];
#pragma unroll
        for (int si = 0; si < 4; si++)
          cp[si] = fmaf(EXP2(acc[mf][si][i2] + mask_bias(wlo, 4 * si)), ri, cp[si]);
      }
    if (i == 3) loadMask(1);   // after last jhi=0 use; covered by next VMCNT_(2)
#pragma unroll
    for (int si = 0; si < 4; si++) {
      float v = cp[si];
      v += __shfl_xor(v, 16);
      v += __shfl_xor(v, 32);
      if (lc == 0) atomicAdd(&colacc[i * 64 + si * 16 + lr], v);
    }
    SBAR();
    cur ^= 1;
  }
  __syncthreads();
  if (t < 512) atomicAdd(&abG[t], colacc[t]);
}

// ---- xbar[h*4+b][d] = sum_s abar[h,b,s] * x[b,s,d] -------------------------
__global__ void k_xbar(const float* __restrict__ x, const float* __restrict__ abar,
                       float* __restrict__ xbar) {
  __shared__ float ab[8][128];
  int bx = blockIdx.x;            // dc(4) * 16 + sc(16)
  int b = blockIdx.y;
  int dc = bx >> 4, sc = bx & 15;
  int t = threadIdx.x;
  int d = dc * 256 + t;
  int sc0 = sc * 128;
  for (int i = t; i < 1024; i += 256) {
    int hh = i >> 7, s = i & 127;
    ab[hh][s] = abar[(hh * 4 + b) * 2048 + sc0 + s];
  }
  __syncthreads();
  float acc[8] = {0,0,0,0,0,0,0,0};
  const float* xp = x + ((long)b * 2048 + sc0) * 1024 + d;
  for (int s = 0; s < 128; s++) {
    float xv = xp[(long)s * 1024];
#pragma unroll
    for (int hh = 0; hh < 8; hh++) acc[hh] += xv * ab[hh][s];
  }
#pragma unroll
  for (int hh = 0; hh < 8; hh++) atomicAdd(&xbar[(hh * 4 + b) * 1024 + d], acc[hh]);
}

// ---- ocat[b][h*128+k] += xbar[h,b,dc*128..+128) @ Wv[h][dc*128..+128)[k] ----
__global__ void k_ov(const float* __restrict__ Wv, const float* __restrict__ xbar,
                     float* __restrict__ ocat) {
  __shared__ float xb[128];
  int hb = blockIdx.x, dc = blockIdx.y;
  int h = hb >> 2, b = hb & 3;
  int k = threadIdx.x;   // 128
  xb[k] = xbar[hb * 1024 + dc * 128 + k];
  __syncthreads();
  float acc = 0.f;
  const float* wp = Wv + (long)h * 131072 + (long)(dc * 128) * 128 + k;
#pragma unroll 8
  for (int d = 0; d < 128; d++) acc += xb[d] * wp[(long)d * 128];
  atomicAdd(&ocat[b * 1024 + h * 128 + k], acc);
}

// ---- out1[b][d] = ocat[b,:] . W_lin[d,:] + b_lin[d] -------------------------
__global__ void k_lin(const float* __restrict__ ocat, const float* __restrict__ Wlin,
                      const float* __restrict__ blin, float* __restrict__ out1) {
  int gw = blockIdx.x * 4 + (threadIdx.x >> 6);   // 0..4095 = b*1024+d
  int l = threadIdx.x & 63;
  int b = gw >> 10, d = gw & 1023;
  const float* o = ocat + b * 1024;
  const float* wr = Wlin + (long)d * 1024;
  float acc = 0.f;
  for (int f = l; f < 1024; f += 64) acc += o[f] * wr[f];
#pragma unroll
  for (int m = 32; m; m >>= 1) acc += __shfl_xor(acc, m);
  if (l == 0) out1[gw] = acc + blin[d];
}

// ---- out[b][c] = out1[b,:] . W_last[c,:] + b_last[c] ------------------------
__global__ void k_last(const float* __restrict__ out1, const float* __restrict__ Wlast,
                       const float* __restrict__ blast, float* __restrict__ out) {
  int gw = blockIdx.x * 4 + (threadIdx.x >> 6);   // 0..511 = b*128+c
  int l = threadIdx.x & 63;
  int b = gw >> 7, c = gw & 127;
  const float* i1 = out1 + b * 1024;
  const float* wr = Wlast + (long)c * 1024;
  float acc = 0.f;
  for (int f = l; f < 1024; f += 64) acc += i1[f] * wr[f];
#pragma unroll
  for (int m = 32; m; m >>= 1) acc += __shfl_xor(acc, m);
  if (l == 0) out[gw] = acc + blast[c];
}

extern "C" void kernel_launch(void* const* d_in, const int* in_sizes, int n_in,
                              void* d_out, int out_size, void* d_ws, size_t ws_size,
                              hipStream_t stream) {
  const float* x     = (const float*)d_in[0];
  const void*  mask  = d_in[1];
  const float* Wq    = (const float*)d_in[2];
  const float* Wk    = (const float*)d_in[3];
  const float* Wv    = (const float*)d_in[4];
  const float* Wlin  = (const float*)d_in[5];
  const float* blin  = (const float*)d_in[6];
  const float* Wlast = (const float*)d_in[7];
  const float* blast = (const float*)d_in[8];
  float* out = (float*)d_out;

  char* ws = (char*)d_ws;
  // ws layout (bytes)
  const size_t OFF_FLAG = 0;                      // 256
  const size_t OFF_BITS = 256;                    // 2,097,152
  const size_t OFF_XBF  = 2097408;                // 16,777,216
  const size_t OFF_WQKT = 18874624;               // 4,194,304
  const size_t OFF_QK   = 23068928;               // 33,554,432
  const size_t OFF_ABAR = 56623360;               // 262,144
  const size_t OFF_XBAR = 56885504;               // 131,072
  const size_t OFF_RSUM = 57016576;               // 262,144
  const size_t OFF_OCAT = 57278720;               // 16,384
  const size_t OFF_OUT1 = 57295104;               // 16,384

  int* flag = (int*)(ws + OFF_FLAG);
  unsigned long long* bits = (unsigned long long*)(ws + OFF_BITS);
  unsigned short* xbf  = (unsigned short*)(ws + OFF_XBF);
  unsigned short* wqkt = (unsigned short*)(ws + OFF_WQKT);
  unsigned short* qkb  = (unsigned short*)(ws + OFF_QK);
  float* abar = (float*)(ws + OFF_ABAR);
  float* xbarp = (float*)(ws + OFF_XBAR);
  float* rsum = (float*)(ws + OFF_RSUM);
  float* ocat = (float*)(ws + OFF_OCAT);
  float* out1 = (float*)(ws + OFF_OUT1);

  // zero abar + xbar + rowsum + ocat (contiguous)
  hipMemsetAsync(ws + OFF_ABAR, 0, 262144 + 131072 + 262144 + 16384, stream);
  k_prep<<<16384, 256, 0, stream>>>((const float4*)x, (uint2*)xbf, Wq, Wk, wqkt,
                                    (const uint32_t*)mask, flag);
  k_bitpack<<<16384, 256, 0, stream>>>(mask, flag, bits);
  k_gemm256<<<256, 512, 0, stream>>>(xbf, wqkt, qkb);
  k_attn_rs<<<dim3(32, 4, 8), 512, 0, stream>>>(qkb, bits, rsum);
  k_attn_cs<<<dim3(32, 4, 8), 512, 0, stream>>>(qkb, bits, rsum, abar);
  k_xbar<<<dim3(64, 4), 256, 0, stream>>>(x, abar, xbarp);
  k_ov<<<dim3(32, 8), 128, 0, stream>>>(Wv, xbarp, ocat);
  k_lin<<<1024, 256, 0, stream>>>(ocat, Wlin, blin, out1);
  k_last<<<128, 256, 0, stream>>>(out1, Wlast, blast, out);
}

// Round 19
// 226.006 us; speedup vs baseline: 1.2148x; 1.2148x over previous
//
#include <hip/hip_runtime.h>
#include <stdint.h>

// Problem constants: B=4, S=2048, D=1024, H=8, DK=128, C=128
typedef __attribute__((ext_vector_type(8))) short short8;
typedef __attribute__((ext_vector_type(4))) float floatx4;

#if defined(__has_builtin)
#if __has_builtin(__builtin_amdgcn_exp2f)
#define EXP2(x) __builtin_amdgcn_exp2f(x)
#endif
#endif
#ifndef EXP2
#define EXP2(x) exp2f(x)
#endif

// sign-extend bit `off` of x to a full 32-bit mask (v_bfe_i32)
#if defined(__has_builtin)
#if __has_builtin(__builtin_amdgcn_sbfe)
#define SBFE1(x, off) __builtin_amdgcn_sbfe((int)(x), (off), 1)
#endif
#endif
#ifndef SBFE1
#define SBFE1(x, off) (((int)((uint32_t)(x) << (31 - (off)))) >> 31)
#endif
// -192.0f bit pattern: masked logits get exp2(acc-192) -> flushed to 0
#define MBIAS_BITS 0xC3400000

__device__ __forceinline__ float mask_bias(uint32_t wlo, int off) {
  int ms = SBFE1(wlo, off);
  union { int i; float f; } u; u.i = ms & (int)MBIAS_BITS;
  return u.f;
}

// 1/sqrt(128) * log2(e)  — folded into W_q so softmax needs only v_exp_f32
#define WQ_SCALE (0.08838834764831845f * 1.4426950408889634f)

// counted waits + raw barrier (T4): never drain vmcnt to 0 in the main loop
#define VMCNT_(n) asm volatile("s_waitcnt vmcnt(" #n ")" ::: "memory")
#define SBAR() do { asm volatile("" ::: "memory"); __builtin_amdgcn_s_barrier(); \
                    asm volatile("" ::: "memory"); } while (0)

__device__ __forceinline__ unsigned short f2bf(float f) {
  union { float f; uint32_t u; } v; v.f = f;
  return (unsigned short)((v.u + 0x7fffu + ((v.u >> 16) & 1u)) >> 16);
}

// async global->LDS DMA, 16B per lane; dst is wave-uniform base (+lane*16 implicit)
__device__ __forceinline__ void gld_lds16(const void* g, void* l) {
  __builtin_amdgcn_global_load_lds((const __attribute__((address_space(1))) uint32_t*)g,
                                   (__attribute__((address_space(3))) uint32_t*)l, 16, 0, 0);
}

// ---- x (f32) -> bf16; block 0 also detects mask element width ---------------
__global__ void k_cvt_x(const float4* __restrict__ x, uint2* __restrict__ xbf,
                        const uint32_t* __restrict__ m, int* __restrict__ flag) {
  long i = (long)blockIdx.x * 256 + threadIdx.x;
  float4 v = x[i];
  uint2 o;
  o.x = (uint32_t)f2bf(v.x) | ((uint32_t)f2bf(v.y) << 16);
  o.y = (uint32_t)f2bf(v.z) | ((uint32_t)f2bf(v.w) << 16);
  xbf[i] = o;
  if (blockIdx.x == 0) {       // block-uniform branch: __syncthreads is legal
    __shared__ int any;
    if (threadIdx.x == 0) any = 0;
    __syncthreads();
    int a = 0;
    for (int j = threadIdx.x; j < 16384; j += 256) a |= (m[j] > 1u) ? 1 : 0;
    if (a) atomicOr(&any, 1);
    __syncthreads();
    if (threadIdx.x == 0) *flag = any;   // 1 => bytes (uint8/bool), 0 => int32
  }
}

// ---- bit-pack mask, ballot-natural layout -----------------------------------
// bit for (row=b*2048+q, s): word row*32 + (s>>8)*4 + (s&3), bitpos (s&255)>>2
__global__ void k_bitpack(const void* __restrict__ mask, const int* __restrict__ flag,
                          unsigned long long* __restrict__ bits) {
  long tid = (long)blockIdx.x * 256 + threadIdx.x;   // each thread: 4 consecutive elems
  int f = *flag;
  int l = threadIdx.x & 63;
  int nib;
  if (f) {
    uchar4 v = ((const uchar4*)mask)[tid];
    nib = (v.x != 0) | ((v.y != 0) << 1) | ((v.z != 0) << 2) | ((v.w != 0) << 3);
  } else {
    int4 v = ((const int4*)mask)[tid];
    nib = (v.x != 0) | ((v.y != 0) << 1) | ((v.z != 0) << 2) | ((v.w != 0) << 3);
  }
  unsigned long long b0 = __ballot((nib & 1) != 0);
  unsigned long long b1 = __ballot((nib & 2) != 0);
  unsigned long long b2 = __ballot((nib & 4) != 0);
  unsigned long long b3 = __ballot((nib & 8) != 0);
  if (l < 4) {
    long wb = (tid * 4) & ~255L;        // wave-base element index
    long row = wb >> 11;                 // (b*2048+q)
    int a = (int)((wb >> 8) & 7);
    unsigned long long val = (l == 0) ? b0 : ((l == 1) ? b1 : ((l == 2) ? b2 : b3));
    bits[row * 32 + a * 4 + l] = val;
  }
}

// ---- W_q,W_k [H,D,DK] -> wqkt[2048][1024] bf16; W_q pre-scaled --------------
__global__ void k_cvt_w(const float* __restrict__ wq, const float* __restrict__ wk,
                        unsigned short* __restrict__ wqkt) {
  int tid = blockIdx.x * 256 + threadIdx.x;   // n*1024 + d
  int n = tid >> 10, d = tid & 1023;
  int isq = (n < 1024);
  const float* src = isq ? wq : wk;
  int nn = n & 1023;
  int h = nn >> 7, dk = nn & 127;
  float v = src[h * 131072 + d * 128 + dk];
  wqkt[tid] = f2bf(isq ? v * WQ_SCALE : v);
}

// ---- GEMM 256x256 tile, proven 2-barrier counted-vmcnt schedule (R15 best) --
__launch_bounds__(512, 2)
__global__ void k_gemm256(const unsigned short* __restrict__ xbf,
                          const unsigned short* __restrict__ wqkt,
                          unsigned short* __restrict__ qk) {
  __shared__ uint4 lds[2][2048];   // 2 x 32KB: A subtiles 0..15, B 16..31
  int bid = blockIdx.x;
  bid = (bid & 7) * 32 + (bid >> 3);          // XCD-chunked swizzle (256 % 8 == 0)
  int m0 = (bid >> 3) * 256, n0 = (bid & 7) * 256;
  int t = threadIdx.x, w = t >> 6, l = t & 63;
  int lr = l & 15, lc = l >> 4;
  int wr = w >> 2, wc = w & 3;                // wave grid 2M x 4N
  floatx4 z = {0.f, 0.f, 0.f, 0.f};
  floatx4 acc[8][4];
#pragma unroll
  for (int ii = 0; ii < 8; ii++)
#pragma unroll
    for (int jj = 0; jj < 4; jj++) acc[ii][jj] = z;

  auto stage = [&](int buf, int k0) {
#pragma unroll
    for (int j = 0; j < 4; j++) {
      int sub = w * 4 + j;   // 0..31: A mi=sub (0..15), B ni=sub-16
      const unsigned short* src = (sub < 16)
        ? xbf + (long)(m0 + sub * 16 + lr) * 1024 + k0 + lc * 8
        : wqkt + (long)(n0 + (sub - 16) * 16 + lr) * 1024 + k0 + lc * 8;
      gld_lds16(src, &lds[buf][sub * 64]);
    }
  };

  stage(0, 0);
  VMCNT_(0);
  SBAR();
  int cur = 0;
  for (int kt = 0; kt < 32; ++kt) {
    if (kt < 31) { stage(cur ^ 1, (kt + 1) * 32); VMCNT_(4); } else { VMCNT_(0); }
    SBAR();
    const unsigned short* al = (const unsigned short*)lds[cur];
    const unsigned short* bl = al + 8192;   // B at byte 16384
    short8 B[4], A0[4], A1[4];
#pragma unroll
    for (int nf = 0; nf < 4; nf++) B[nf] = *(const short8*)(bl + (wc * 4 + nf) * 512 + l * 8);
#pragma unroll
    for (int mf = 0; mf < 4; mf++) A0[mf] = *(const short8*)(al + (wr * 8 + mf) * 512 + l * 8);
    __builtin_amdgcn_s_setprio(1);
#pragma unroll
    for (int mf = 0; mf < 4; mf++)
#pragma unroll
      for (int nf = 0; nf < 4; nf++)
        acc[mf][nf] = __builtin_amdgcn_mfma_f32_16x16x32_bf16(A0[mf], B[nf], acc[mf][nf], 0, 0, 0);
#pragma unroll
    for (int mf = 0; mf < 4; mf++) A1[mf] = *(const short8*)(al + (wr * 8 + 4 + mf) * 512 + l * 8);
#pragma unroll
    for (int mf = 0; mf < 4; mf++)
#pragma unroll
      for (int nf = 0; nf < 4; nf++)
        acc[4 + mf][nf] = __builtin_amdgcn_mfma_f32_16x16x32_bf16(A1[mf], B[nf], acc[4 + mf][nf], 0, 0, 0);
    __builtin_amdgcn_s_setprio(0);
    SBAR();
    cur ^= 1;
  }
#pragma unroll
  for (int mf = 0; mf < 8; mf++)
#pragma unroll
    for (int nf = 0; nf < 4; nf++)
#pragma unroll
      for (int i = 0; i < 4; i++) {
        int row = m0 + wr * 128 + mf * 16 + lc * 4 + i;
        int col = n0 + wc * 64 + nf * 16 + lr;
        qk[(long)row * 2048 + col] = f2bf(acc[mf][nf][i]);
      }
}

// ---- attn pass A: rowsum[h*4+b][q] += sum_s exp2(logit + maskbias) ----------
// 512 thr = 8 waves; q-tile 256 (wave owns 32 q), s-tile 512 in 8 steps of 64.
__launch_bounds__(512, 4)
__global__ void k_attn_rs(const unsigned short* __restrict__ qk,
                          const unsigned long long* __restrict__ bits,
                          float* __restrict__ rowsum) {
  __shared__ uint4 k4[2][1024];                 // 2 x 16KB K tile (64 keys x 128 dk)
  int qt = blockIdx.x >> 2, st = blockIdx.x & 3;
  int b = blockIdx.y, h = blockIdx.z;
  int t = threadIdx.x, w = t >> 6, l = t & 63;
  int lr = l & 15, lc = l >> 4;
  int q0 = qt * 256, sbase = st * 512;
  const unsigned short* Q = qk + (long)b * 4194304 + h * 128;
  const unsigned short* K = qk + (long)b * 4194304 + 1024 + h * 128;
  const unsigned long long* browB = bits + ((long)b * 2048 + q0) * 32 + (sbase >> 8) * 4;

  short8 qf[2][4];
#pragma unroll
  for (int mf = 0; mf < 2; mf++)
#pragma unroll
    for (int ki = 0; ki < 4; ki++)
      qf[mf][ki] = *(const short8*)(Q + (long)(q0 + w * 32 + mf * 16 + lr) * 2048 + ki * 32 + lc * 8);

  auto stageK = [&](int buf, int s0g) {
#pragma unroll
    for (int j = 0; j < 2; j++) {
      int sub = w * 2 + j, si = sub >> 2, ki = sub & 3;
      gld_lds16(K + (long)(s0g + si * 16 + lr) * 2048 + ki * 32 + lc * 8, &k4[buf][sub * 64]);
    }
  };

  stageK(0, sbase);
  VMCNT_(0);
  SBAR();

  floatx4 z = {0.f, 0.f, 0.f, 0.f};
  float lsum[2][4] = {{0,0,0,0},{0,0,0,0}};
  unsigned long long mwreg[8];
  int cur = 0;
  for (int i = 0; i < 8; ++i) {
    int s0g = sbase + i * 64;
    if (i < 7) { stageK(cur ^ 1, s0g + 64); VMCNT_(2); } else { VMCNT_(0); }
    SBAR();
    if ((i & 3) == 0) {          // refresh per-lane mask regs from global (L2)
      int jhi = i >> 2;
#pragma unroll
      for (int mf = 0; mf < 2; mf++)
#pragma unroll
        for (int i2 = 0; i2 < 4; i2++)
          mwreg[mf * 4 + i2] =
              browB[(long)(w * 32 + mf * 16 + lc * 4 + i2) * 32 + jhi * 4 + (lr & 3)];
    }
    const unsigned short* kl = (const unsigned short*)k4[cur];
    floatx4 acc[2][4];
#pragma unroll
    for (int ii = 0; ii < 2; ii++)
#pragma unroll
      for (int jj = 0; jj < 4; jj++) acc[ii][jj] = z;
    __builtin_amdgcn_s_setprio(1);
#pragma unroll
    for (int ki = 0; ki < 4; ki++) {
      short8 bb[4];
#pragma unroll
      for (int si = 0; si < 4; si++) bb[si] = *(const short8*)(kl + (si * 4 + ki) * 512 + l * 8);
#pragma unroll
      for (int mf = 0; mf < 2; mf++)
#pragma unroll
        for (int si = 0; si < 4; si++)
          acc[mf][si] = __builtin_amdgcn_mfma_f32_16x16x32_bf16(qf[mf][ki], bb[si], acc[mf][si], 0, 0, 0);
    }
    __builtin_amdgcn_s_setprio(0);
    int shb = (i & 3) * 16 + (lr >> 2);
#pragma unroll
    for (int mf = 0; mf < 2; mf++)
#pragma unroll
      for (int i2 = 0; i2 < 4; i2++) {
        uint32_t wlo = (uint32_t)(mwreg[mf * 4 + i2] >> shb);
        float p = 0.f;
#pragma unroll
        for (int si = 0; si < 4; si++)
          p += EXP2(acc[mf][si][i2] + mask_bias(wlo, 4 * si));
        lsum[mf][i2] += p;
      }
    SBAR();
    cur ^= 1;
  }
#pragma unroll
  for (int mf = 0; mf < 2; mf++)
#pragma unroll
    for (int i2 = 0; i2 < 4; i2++) {
      float v = lsum[mf][i2];
      v += __shfl_xor(v, 1); v += __shfl_xor(v, 2);
      v += __shfl_xor(v, 4); v += __shfl_xor(v, 8);
      if (lr == 0)
        atomicAdd(&rowsum[((h * 4 + b) << 11) + q0 + w * 32 + mf * 16 + lc * 4 + i2], v);
    }
}

// ---- attn pass B: abar[h*4+b][s] += sum_q exp2(logit+maskbias)*rinv_q -------
__launch_bounds__(512, 4)
__global__ void k_attn_cs(const unsigned short* __restrict__ qk,
                          const unsigned long long* __restrict__ bits,
                          const float* __restrict__ rowsum,
                          float* __restrict__ abar) {
  __shared__ uint4 k4[2][1024];
  __shared__ float colacc[512];
  int qt = blockIdx.x >> 2, st = blockIdx.x & 3;
  int b = blockIdx.y, h = blockIdx.z;
  int t = threadIdx.x, w = t >> 6, l = t & 63;
  int lr = l & 15, lc = l >> 4;
  int q0 = qt * 256, sbase = st * 512;
  const unsigned short* Q = qk + (long)b * 4194304 + h * 128;
  const unsigned short* K = qk + (long)b * 4194304 + 1024 + h * 128;
  const unsigned long long* browB = bits + ((long)b * 2048 + q0) * 32 + (sbase >> 8) * 4;
  float* abG = abar + ((h * 4 + b) << 11) + sbase;

  short8 qf[2][4];
#pragma unroll
  for (int mf = 0; mf < 2; mf++)
#pragma unroll
    for (int ki = 0; ki < 4; ki++)
      qf[mf][ki] = *(const short8*)(Q + (long)(q0 + w * 32 + mf * 16 + lr) * 2048 + ki * 32 + lc * 8);

  float rinv[2][4];
#pragma unroll
  for (int mf = 0; mf < 2; mf++)
#pragma unroll
    for (int i2 = 0; i2 < 4; i2++)
      rinv[mf][i2] = 1.f / (rowsum[((h * 4 + b) << 11) + q0 + w * 32 + mf * 16 + lc * 4 + i2] * 2048.f);

  auto stageK = [&](int buf, int s0g) {
#pragma unroll
    for (int j = 0; j < 2; j++) {
      int sub = w * 2 + j, si = sub >> 2, ki = sub & 3;
      gld_lds16(K + (long)(s0g + si * 16 + lr) * 2048 + ki * 32 + lc * 8, &k4[buf][sub * 64]);
    }
  };

  stageK(0, sbase);
  colacc[t < 512 ? t : 0] = 0.f;
  VMCNT_(0);
  SBAR();

  floatx4 z = {0.f, 0.f, 0.f, 0.f};
  unsigned long long mwreg[8];
  int cur = 0;
  for (int i = 0; i < 8; ++i) {
    int s0g = sbase + i * 64;
    if (i < 7) { stageK(cur ^ 1, s0g + 64); VMCNT_(2); } else { VMCNT_(0); }
    SBAR();
    if ((i & 3) == 0) {
      int jhi = i >> 2;
#pragma unroll
      for (int mf = 0; mf < 2; mf++)
#pragma unroll
        for (int i2 = 0; i2 < 4; i2++)
          mwreg[mf * 4 + i2] =
              browB[(long)(w * 32 + mf * 16 + lc * 4 + i2) * 32 + jhi * 4 + (lr & 3)];
    }
    const unsigned short* kl = (const unsigned short*)k4[cur];
    floatx4 acc[2][4];
#pragma unroll
    for (int ii = 0; ii < 2; ii++)
#pragma unroll
      for (int jj = 0; jj < 4; jj++) acc[ii][jj] = z;
    __builtin_amdgcn_s_setprio(1);
#pragma unroll
    for (int ki = 0; ki < 4; ki++) {
      short8 bb[4];
#pragma unroll
      for (int si = 0; si < 4; si++) bb[si] = *(const short8*)(kl + (si * 4 + ki) * 512 + l * 8);
#pragma unroll
      for (int mf = 0; mf < 2; mf++)
#pragma unroll
        for (int si = 0; si < 4; si++)
          acc[mf][si] = __builtin_amdgcn_mfma_f32_16x16x32_bf16(qf[mf][ki], bb[si], acc[mf][si], 0, 0, 0);
    }
    __builtin_amdgcn_s_setprio(0);
    int shb = (i & 3) * 16 + (lr >> 2);
    float cp[4] = {0.f, 0.f, 0.f, 0.f};
#pragma unroll
    for (int mf = 0; mf < 2; mf++)
#pragma unroll
      for (int i2 = 0; i2 < 4; i2++) {
        uint32_t wlo = (uint32_t)(mwreg[mf * 4 + i2] >> shb);
        float ri = rinv[mf][i2];
#pragma unroll
        for (int si = 0; si < 4; si++)
          cp[si] = fmaf(EXP2(acc[mf][si][i2] + mask_bias(wlo, 4 * si)), ri, cp[si]);
      }
#pragma unroll
    for (int si = 0; si < 4; si++) {
      float v = cp[si];
      v += __shfl_xor(v, 16);
      v += __shfl_xor(v, 32);
      if (lc == 0) atomicAdd(&colacc[i * 64 + si * 16 + lr], v);
    }
    SBAR();
    cur ^= 1;
  }
  __syncthreads();
  if (t < 512) atomicAdd(&abG[t], colacc[t]);
}

// ---- xbar[h*4+b][d] = sum_s abar[h,b,s] * x[b,s,d] -------------------------
__global__ void k_xbar(const float* __restrict__ x, const float* __restrict__ abar,
                       float* __restrict__ xbar) {
  __shared__ float ab[8][128];
  int bx = blockIdx.x;            // dc(4) * 16 + sc(16)
  int b = blockIdx.y;
  int dc = bx >> 4, sc = bx & 15;
  int t = threadIdx.x;
  int d = dc * 256 + t;
  int sc0 = sc * 128;
  for (int i = t; i < 1024; i += 256) {
    int hh = i >> 7, s = i & 127;
    ab[hh][s] = abar[(hh * 4 + b) * 2048 + sc0 + s];
  }
  __syncthreads();
  float acc[8] = {0,0,0,0,0,0,0,0};
  const float* xp = x + ((long)b * 2048 + sc0) * 1024 + d;
  for (int s = 0; s < 128; s++) {
    float xv = xp[(long)s * 1024];
#pragma unroll
    for (int hh = 0; hh < 8; hh++) acc[hh] += xv * ab[hh][s];
  }
#pragma unroll
  for (int hh = 0; hh < 8; hh++) atomicAdd(&xbar[(hh * 4 + b) * 1024 + d], acc[hh]);
}

// ---- ocat[b][h*128+k] += xbar[h,b,dc*128..+128) @ Wv[h][dc*128..+128)[k] ----
__global__ void k_ov(const float* __restrict__ Wv, const float* __restrict__ xbar,
                     float* __restrict__ ocat) {
  __shared__ float xb[128];
  int hb = blockIdx.x, dc = blockIdx.y;
  int h = hb >> 2, b = hb & 3;
  int k = threadIdx.x;   // 128
  xb[k] = xbar[hb * 1024 + dc * 128 + k];
  __syncthreads();
  float acc = 0.f;
  const float* wp = Wv + (long)h * 131072 + (long)(dc * 128) * 128 + k;
#pragma unroll 8
  for (int d = 0; d < 128; d++) acc += xb[d] * wp[(long)d * 128];
  atomicAdd(&ocat[b * 1024 + h * 128 + k], acc);
}

// ---- out1[b][d] = ocat[b,:] . W_lin[d,:] + b_lin[d] -------------------------
__global__ void k_lin(const float* __restrict__ ocat, const float* __restrict__ Wlin,
                      const float* __restrict__ blin, float* __restrict__ out1) {
  int gw = blockIdx.x * 4 + (threadIdx.x >> 6);   // 0..4095 = b*1024+d
  int l = threadIdx.x & 63;
  int b = gw >> 10, d = gw & 1023;
  const float* o = ocat + b * 1024;
  const float* wr = Wlin + (long)d * 1024;
  float acc = 0.f;
  for (int f = l; f < 1024; f += 64) acc += o[f] * wr[f];
#pragma unroll
  for (int m = 32; m; m >>= 1) acc += __shfl_xor(acc, m);
  if (l == 0) out1[gw] = acc + blin[d];
}

// ---- out[b][c] = out1[b,:] . W_last[c,:] + b_last[c] ------------------------
__global__ void k_last(const float* __restrict__ out1, const float* __restrict__ Wlast,
                       const float* __restrict__ blast, float* __restrict__ out) {
  int gw = blockIdx.x * 4 + (threadIdx.x >> 6);   // 0..511 = b*128+c
  int l = threadIdx.x & 63;
  int b = gw >> 7, c = gw & 127;
  const float* i1 = out1 + b * 1024;
  const float* wr = Wlast + (long)c * 1024;
  float acc = 0.f;
  for (int f = l; f < 1024; f += 64) acc += i1[f] * wr[f];
#pragma unroll
  for (int m = 32; m; m >>= 1) acc += __shfl_xor(acc, m);
  if (l == 0) out[gw] = acc + blast[c];
}

extern "C" void kernel_launch(void* const* d_in, const int* in_sizes, int n_in,
                              void* d_out, int out_size, void* d_ws, size_t ws_size,
                              hipStream_t stream) {
  const float* x     = (const float*)d_in[0];
  const void*  mask  = d_in[1];
  const float* Wq    = (const float*)d_in[2];
  const float* Wk    = (const float*)d_in[3];
  const float* Wv    = (const float*)d_in[4];
  const float* Wlin  = (const float*)d_in[5];
  const float* blin  = (const float*)d_in[6];
  const float* Wlast = (const float*)d_in[7];
  const float* blast = (const float*)d_in[8];
  float* out = (float*)d_out;

  char* ws = (char*)d_ws;
  // ws layout (bytes)
  const size_t OFF_FLAG = 0;                      // 256
  const size_t OFF_BITS = 256;                    // 2,097,152
  const size_t OFF_XBF  = 2097408;                // 16,777,216
  const size_t OFF_WQKT = 18874624;               // 4,194,304
  const size_t OFF_QK   = 23068928;               // 33,554,432
  const size_t OFF_ABAR = 56623360;               // 262,144
  const size_t OFF_XBAR = 56885504;               // 131,072
  const size_t OFF_RSUM = 57016576;               // 262,144
  const size_t OFF_OCAT = 57278720;               // 16,384
  const size_t OFF_OUT1 = 57295104;               // 16,384

  int* flag = (int*)(ws + OFF_FLAG);
  unsigned long long* bits = (unsigned long long*)(ws + OFF_BITS);
  unsigned short* xbf  = (unsigned short*)(ws + OFF_XBF);
  unsigned short* wqkt = (unsigned short*)(ws + OFF_WQKT);
  unsigned short* qkb  = (unsigned short*)(ws + OFF_QK);
  float* abar = (float*)(ws + OFF_ABAR);
  float* xbarp = (float*)(ws + OFF_XBAR);
  float* rsum = (float*)(ws + OFF_RSUM);
  float* ocat = (float*)(ws + OFF_OCAT);
  float* out1 = (float*)(ws + OFF_OUT1);

  // zero abar + xbar + rowsum + ocat (contiguous)
  hipMemsetAsync(ws + OFF_ABAR, 0, 262144 + 131072 + 262144 + 16384, stream);
  k_cvt_x<<<8192, 256, 0, stream>>>((const float4*)x, (uint2*)xbf, (const uint32_t*)mask, flag);
  k_bitpack<<<16384, 256, 0, stream>>>(mask, flag, bits);
  k_cvt_w<<<8192, 256, 0, stream>>>(Wq, Wk, wqkt);
  k_gemm256<<<256, 512, 0, stream>>>(xbf, wqkt, qkb);
  k_attn_rs<<<dim3(32, 4, 8), 512, 0, stream>>>(qkb, bits, rsum);
  k_attn_cs<<<dim3(32, 4, 8), 512, 0, stream>>>(qkb, bits, rsum, abar);
  k_xbar<<<dim3(64, 4), 256, 0, stream>>>(x, abar, xbarp);
  k_ov<<<dim3(32, 8), 128, 0, stream>>>(Wv, xbarp, ocat);
  k_lin<<<1024, 256, 0, stream>>>(ocat, Wlin, blin, out1);
  k_last<<<128, 256, 0, stream>>>(out1, Wlast, blast, out);
}

// Round 20
// 221.228 us; speedup vs baseline: 1.2411x; 1.0216x over previous
//
#include <hip/hip_runtime.h>
#include <stdint.h>

// Problem constants: B=4, S=2048, D=1024, H=8, DK=128, C=128
typedef __attribute__((ext_vector_type(8))) short short8;
typedef __attribute__((ext_vector_type(4))) float floatx4;

#if defined(__has_builtin)
#if __has_builtin(__builtin_amdgcn_exp2f)
#define EXP2(x) __builtin_amdgcn_exp2f(x)
#endif
#endif
#ifndef EXP2
#define EXP2(x) exp2f(x)
#endif

// sign-extend bit `off` of x to a full 32-bit mask (v_bfe_i32)
#if defined(__has_builtin)
#if __has_builtin(__builtin_amdgcn_sbfe)
#define SBFE1(x, off) __builtin_amdgcn_sbfe((int)(x), (off), 1)
#endif
#endif
#ifndef SBFE1
#define SBFE1(x, off) (((int)((uint32_t)(x) << (31 - (off)))) >> 31)
#endif
// -192.0f bit pattern: masked logits get exp2(acc-192) -> flushed to 0
#define MBIAS_BITS 0xC3400000

__device__ __forceinline__ float mask_bias(uint32_t wlo, int off) {
  int ms = SBFE1(wlo, off);
  union { int i; float f; } u; u.i = ms & (int)MBIAS_BITS;
  return u.f;
}

// 1/sqrt(128) * log2(e)  — folded into W_q so softmax needs only v_exp_f32
#define WQ_SCALE (0.08838834764831845f * 1.4426950408889634f)

// counted waits + raw barrier (T4): never drain vmcnt to 0 in the main loop
#define VMCNT_(n) asm volatile("s_waitcnt vmcnt(" #n ")" ::: "memory")
#define SBAR() do { asm volatile("" ::: "memory"); __builtin_amdgcn_s_barrier(); \
                    asm volatile("" ::: "memory"); } while (0)

__device__ __forceinline__ unsigned short f2bf(float f) {
  union { float f; uint32_t u; } v; v.f = f;
  return (unsigned short)((v.u + 0x7fffu + ((v.u >> 16) & 1u)) >> 16);
}

// async global->LDS DMA, 16B per lane; dst is wave-uniform base (+lane*16 implicit)
__device__ __forceinline__ void gld_lds16(const void* g, void* l) {
  __builtin_amdgcn_global_load_lds((const __attribute__((address_space(1))) uint32_t*)g,
                                   (__attribute__((address_space(3))) uint32_t*)l, 16, 0, 0);
}

// XCD-chunked decode for attention grids (flat 1024 blocks):
// xcd = g%8; all 32 (qt,st) blocks of one (b,h) land on ONE XCD -> K/Q L2-hit.
__device__ __forceinline__ void attn_decode(int g, int& qt, int& st, int& b, int& h) {
  int xcd = g & 7, slot = g >> 3;          // 128 slots per XCD
  int hb = xcd + 8 * (slot >> 5);          // 4 hb groups per XCD
  int qtst = slot & 31;
  qt = qtst >> 2; st = qtst & 3;
  h = hb >> 2; b = hb & 3;
}

// ---- x (f32) -> bf16; block 0 also detects mask element width ---------------
__global__ void k_cvt_x(const float4* __restrict__ x, uint2* __restrict__ xbf,
                        const uint32_t* __restrict__ m, int* __restrict__ flag) {
  long i = (long)blockIdx.x * 256 + threadIdx.x;
  float4 v = x[i];
  uint2 o;
  o.x = (uint32_t)f2bf(v.x) | ((uint32_t)f2bf(v.y) << 16);
  o.y = (uint32_t)f2bf(v.z) | ((uint32_t)f2bf(v.w) << 16);
  xbf[i] = o;
  if (blockIdx.x == 0) {       // block-uniform branch: __syncthreads is legal
    __shared__ int any;
    if (threadIdx.x == 0) any = 0;
    __syncthreads();
    int a = 0;
    for (int j = threadIdx.x; j < 16384; j += 256) a |= (m[j] > 1u) ? 1 : 0;
    if (a) atomicOr(&any, 1);
    __syncthreads();
    if (threadIdx.x == 0) *flag = any;   // 1 => bytes (uint8/bool), 0 => int32
  }
}

// ---- bit-pack mask, ballot-natural layout -----------------------------------
// bit for (row=b*2048+q, s): word row*32 + (s>>8)*4 + (s&3), bitpos (s&255)>>2
__global__ void k_bitpack(const void* __restrict__ mask, const int* __restrict__ flag,
                          unsigned long long* __restrict__ bits) {
  long tid = (long)blockIdx.x * 256 + threadIdx.x;   // each thread: 4 consecutive elems
  int f = *flag;
  int l = threadIdx.x & 63;
  int nib;
  if (f) {
    uchar4 v = ((const uchar4*)mask)[tid];
    nib = (v.x != 0) | ((v.y != 0) << 1) | ((v.z != 0) << 2) | ((v.w != 0) << 3);
  } else {
    int4 v = ((const int4*)mask)[tid];
    nib = (v.x != 0) | ((v.y != 0) << 1) | ((v.z != 0) << 2) | ((v.w != 0) << 3);
  }
  unsigned long long b0 = __ballot((nib & 1) != 0);
  unsigned long long b1 = __ballot((nib & 2) != 0);
  unsigned long long b2 = __ballot((nib & 4) != 0);
  unsigned long long b3 = __ballot((nib & 8) != 0);
  if (l < 4) {
    long wb = (tid * 4) & ~255L;        // wave-base element index
    long row = wb >> 11;                 // (b*2048+q)
    int a = (int)((wb >> 8) & 7);
    unsigned long long val = (l == 0) ? b0 : ((l == 1) ? b1 : ((l == 2) ? b2 : b3));
    bits[row * 32 + a * 4 + l] = val;
  }
}

// ---- W_q,W_k [H,D,DK] -> wqkt[2048][1024] bf16; W_q pre-scaled --------------
__global__ void k_cvt_w(const float* __restrict__ wq, const float* __restrict__ wk,
                        unsigned short* __restrict__ wqkt) {
  int tid = blockIdx.x * 256 + threadIdx.x;   // n*1024 + d
  int n = tid >> 10, d = tid & 1023;
  int isq = (n < 1024);
  const float* src = isq ? wq : wk;
  int nn = n & 1023;
  int h = nn >> 7, dk = nn & 127;
  float v = src[h * 131072 + d * 128 + dk];
  wqkt[tid] = f2bf(isq ? v * WQ_SCALE : v);
}

// ---- GEMM 256x256 tile, proven 2-barrier counted-vmcnt schedule (R15 best) --
__launch_bounds__(512, 2)
__global__ void k_gemm256(const unsigned short* __restrict__ xbf,
                          const unsigned short* __restrict__ wqkt,
                          unsigned short* __restrict__ qk) {
  __shared__ uint4 lds[2][2048];   // 2 x 32KB: A subtiles 0..15, B 16..31
  int bid = blockIdx.x;
  bid = (bid & 7) * 32 + (bid >> 3);          // XCD-chunked swizzle (256 % 8 == 0)
  int m0 = (bid >> 3) * 256, n0 = (bid & 7) * 256;
  int t = threadIdx.x, w = t >> 6, l = t & 63;
  int lr = l & 15, lc = l >> 4;
  int wr = w >> 2, wc = w & 3;                // wave grid 2M x 4N
  floatx4 z = {0.f, 0.f, 0.f, 0.f};
  floatx4 acc[8][4];
#pragma unroll
  for (int ii = 0; ii < 8; ii++)
#pragma unroll
    for (int jj = 0; jj < 4; jj++) acc[ii][jj] = z;

  auto stage = [&](int buf, int k0) {
#pragma unroll
    for (int j = 0; j < 4; j++) {
      int sub = w * 4 + j;   // 0..31: A mi=sub (0..15), B ni=sub-16
      const unsigned short* src = (sub < 16)
        ? xbf + (long)(m0 + sub * 16 + lr) * 1024 + k0 + lc * 8
        : wqkt + (long)(n0 + (sub - 16) * 16 + lr) * 1024 + k0 + lc * 8;
      gld_lds16(src, &lds[buf][sub * 64]);
    }
  };

  stage(0, 0);
  VMCNT_(0);
  SBAR();
  int cur = 0;
  for (int kt = 0; kt < 32; ++kt) {
    if (kt < 31) { stage(cur ^ 1, (kt + 1) * 32); VMCNT_(4); } else { VMCNT_(0); }
    SBAR();
    const unsigned short* al = (const unsigned short*)lds[cur];
    const unsigned short* bl = al + 8192;   // B at byte 16384
    short8 B[4], A0[4], A1[4];
#pragma unroll
    for (int nf = 0; nf < 4; nf++) B[nf] = *(const short8*)(bl + (wc * 4 + nf) * 512 + l * 8);
#pragma unroll
    for (int mf = 0; mf < 4; mf++) A0[mf] = *(const short8*)(al + (wr * 8 + mf) * 512 + l * 8);
    __builtin_amdgcn_s_setprio(1);
#pragma unroll
    for (int mf = 0; mf < 4; mf++)
#pragma unroll
      for (int nf = 0; nf < 4; nf++)
        acc[mf][nf] = __builtin_amdgcn_mfma_f32_16x16x32_bf16(A0[mf], B[nf], acc[mf][nf], 0, 0, 0);
#pragma unroll
    for (int mf = 0; mf < 4; mf++) A1[mf] = *(const short8*)(al + (wr * 8 + 4 + mf) * 512 + l * 8);
#pragma unroll
    for (int mf = 0; mf < 4; mf++)
#pragma unroll
      for (int nf = 0; nf < 4; nf++)
        acc[4 + mf][nf] = __builtin_amdgcn_mfma_f32_16x16x32_bf16(A1[mf], B[nf], acc[4 + mf][nf], 0, 0, 0);
    __builtin_amdgcn_s_setprio(0);
    SBAR();
    cur ^= 1;
  }
#pragma unroll
  for (int mf = 0; mf < 8; mf++)
#pragma unroll
    for (int nf = 0; nf < 4; nf++)
#pragma unroll
      for (int i = 0; i < 4; i++) {
        int row = m0 + wr * 128 + mf * 16 + lc * 4 + i;
        int col = n0 + wc * 64 + nf * 16 + lr;
        qk[(long)row * 2048 + col] = f2bf(acc[mf][nf][i]);
      }
}

// ---- attn pass A: rowsum[h*4+b][q] += sum_s exp2(logit + maskbias) ----------
// flat grid 1024, XCD-chunked (b,h) decode; otherwise R17-exact.
__launch_bounds__(512, 4)
__global__ void k_attn_rs(const unsigned short* __restrict__ qk,
                          const unsigned long long* __restrict__ bits,
                          float* __restrict__ rowsum) {
  __shared__ uint4 k4[2][1024];                 // 2 x 16KB K tile (64 keys x 128 dk)
  int qt, st, b, h;
  attn_decode(blockIdx.x, qt, st, b, h);
  int t = threadIdx.x, w = t >> 6, l = t & 63;
  int lr = l & 15, lc = l >> 4;
  int q0 = qt * 256, sbase = st * 512;
  const unsigned short* Q = qk + (long)b * 4194304 + h * 128;
  const unsigned short* K = qk + (long)b * 4194304 + 1024 + h * 128;
  const unsigned long long* browB = bits + ((long)b * 2048 + q0) * 32 + (sbase >> 8) * 4;

  short8 qf[2][4];
#pragma unroll
  for (int mf = 0; mf < 2; mf++)
#pragma unroll
    for (int ki = 0; ki < 4; ki++)
      qf[mf][ki] = *(const short8*)(Q + (long)(q0 + w * 32 + mf * 16 + lr) * 2048 + ki * 32 + lc * 8);

  auto stageK = [&](int buf, int s0g) {
#pragma unroll
    for (int j = 0; j < 2; j++) {
      int sub = w * 2 + j, si = sub >> 2, ki = sub & 3;
      gld_lds16(K + (long)(s0g + si * 16 + lr) * 2048 + ki * 32 + lc * 8, &k4[buf][sub * 64]);
    }
  };

  stageK(0, sbase);
  VMCNT_(0);
  SBAR();

  floatx4 z = {0.f, 0.f, 0.f, 0.f};
  float lsum[2][4] = {{0,0,0,0},{0,0,0,0}};
  unsigned long long mwreg[8];
  int cur = 0;
  for (int i = 0; i < 8; ++i) {
    int s0g = sbase + i * 64;
    if (i < 7) { stageK(cur ^ 1, s0g + 64); VMCNT_(2); } else { VMCNT_(0); }
    SBAR();
    if ((i & 3) == 0) {          // refresh per-lane mask regs from global (L2)
      int jhi = i >> 2;
#pragma unroll
      for (int mf = 0; mf < 2; mf++)
#pragma unroll
        for (int i2 = 0; i2 < 4; i2++)
          mwreg[mf * 4 + i2] =
              browB[(long)(w * 32 + mf * 16 + lc * 4 + i2) * 32 + jhi * 4 + (lr & 3)];
    }
    const unsigned short* kl = (const unsigned short*)k4[cur];
    floatx4 acc[2][4];
#pragma unroll
    for (int ii = 0; ii < 2; ii++)
#pragma unroll
      for (int jj = 0; jj < 4; jj++) acc[ii][jj] = z;
    __builtin_amdgcn_s_setprio(1);
#pragma unroll
    for (int ki = 0; ki < 4; ki++) {
      short8 bb[4];
#pragma unroll
      for (int si = 0; si < 4; si++) bb[si] = *(const short8*)(kl + (si * 4 + ki) * 512 + l * 8);
#pragma unroll
      for (int mf = 0; mf < 2; mf++)
#pragma unroll
        for (int si = 0; si < 4; si++)
          acc[mf][si] = __builtin_amdgcn_mfma_f32_16x16x32_bf16(qf[mf][ki], bb[si], acc[mf][si], 0, 0, 0);
    }
    __builtin_amdgcn_s_setprio(0);
    int shb = (i & 3) * 16 + (lr >> 2);
#pragma unroll
    for (int mf = 0; mf < 2; mf++)
#pragma unroll
      for (int i2 = 0; i2 < 4; i2++) {
        uint32_t wlo = (uint32_t)(mwreg[mf * 4 + i2] >> shb);
        float p = 0.f;
#pragma unroll
        for (int si = 0; si < 4; si++)
          p += EXP2(acc[mf][si][i2] + mask_bias(wlo, 4 * si));
        lsum[mf][i2] += p;
      }
    SBAR();
    cur ^= 1;
  }
#pragma unroll
  for (int mf = 0; mf < 2; mf++)
#pragma unroll
    for (int i2 = 0; i2 < 4; i2++) {
      float v = lsum[mf][i2];
      v += __shfl_xor(v, 1); v += __shfl_xor(v, 2);
      v += __shfl_xor(v, 4); v += __shfl_xor(v, 8);
      if (lr == 0)
        atomicAdd(&rowsum[((h * 4 + b) << 11) + q0 + w * 32 + mf * 16 + lc * 4 + i2], v);
    }
}

// ---- attn pass B: abar[h*4+b][s] += sum_q exp2(logit+maskbias)*rinv_q -------
__launch_bounds__(512, 4)
__global__ void k_attn_cs(const unsigned short* __restrict__ qk,
                          const unsigned long long* __restrict__ bits,
                          const float* __restrict__ rowsum,
                          float* __restrict__ abar) {
  __shared__ uint4 k4[2][1024];
  __shared__ float colacc[512];
  int qt, st, b, h;
  attn_decode(blockIdx.x, qt, st, b, h);
  int t = threadIdx.x, w = t >> 6, l = t & 63;
  int lr = l & 15, lc = l >> 4;
  int q0 = qt * 256, sbase = st * 512;
  const unsigned short* Q = qk + (long)b * 4194304 + h * 128;
  const unsigned short* K = qk + (long)b * 4194304 + 1024 + h * 128;
  const unsigned long long* browB = bits + ((long)b * 2048 + q0) * 32 + (sbase >> 8) * 4;
  float* abG = abar + ((h * 4 + b) << 11) + sbase;

  short8 qf[2][4];
#pragma unroll
  for (int mf = 0; mf < 2; mf++)
#pragma unroll
    for (int ki = 0; ki < 4; ki++)
      qf[mf][ki] = *(const short8*)(Q + (long)(q0 + w * 32 + mf * 16 + lr) * 2048 + ki * 32 + lc * 8);

  float rinv[2][4];
#pragma unroll
  for (int mf = 0; mf < 2; mf++)
#pragma unroll
    for (int i2 = 0; i2 < 4; i2++)
      rinv[mf][i2] = 1.f / (rowsum[((h * 4 + b) << 11) + q0 + w * 32 + mf * 16 + lc * 4 + i2] * 2048.f);

  auto stageK = [&](int buf, int s0g) {
#pragma unroll
    for (int j = 0; j < 2; j++) {
      int sub = w * 2 + j, si = sub >> 2, ki = sub & 3;
      gld_lds16(K + (long)(s0g + si * 16 + lr) * 2048 + ki * 32 + lc * 8, &k4[buf][sub * 64]);
    }
  };

  stageK(0, sbase);
  colacc[t < 512 ? t : 0] = 0.f;
  VMCNT_(0);
  SBAR();

  floatx4 z = {0.f, 0.f, 0.f, 0.f};
  unsigned long long mwreg[8];
  int cur = 0;
  for (int i = 0; i < 8; ++i) {
    int s0g = sbase + i * 64;
    if (i < 7) { stageK(cur ^ 1, s0g + 64); VMCNT_(2); } else { VMCNT_(0); }
    SBAR();
    if ((i & 3) == 0) {
      int jhi = i >> 2;
#pragma unroll
      for (int mf = 0; mf < 2; mf++)
#pragma unroll
        for (int i2 = 0; i2 < 4; i2++)
          mwreg[mf * 4 + i2] =
              browB[(long)(w * 32 + mf * 16 + lc * 4 + i2) * 32 + jhi * 4 + (lr & 3)];
    }
    const unsigned short* kl = (const unsigned short*)k4[cur];
    floatx4 acc[2][4];
#pragma unroll
    for (int ii = 0; ii < 2; ii++)
#pragma unroll
      for (int jj = 0; jj < 4; jj++) acc[ii][jj] = z;
    __builtin_amdgcn_s_setprio(1);
#pragma unroll
    for (int ki = 0; ki < 4; ki++) {
      short8 bb[4];
#pragma unroll
      for (int si = 0; si < 4; si++) bb[si] = *(const short8*)(kl + (si * 4 + ki) * 512 + l * 8);
#pragma unroll
      for (int mf = 0; mf < 2; mf++)
#pragma unroll
        for (int si = 0; si < 4; si++)
          acc[mf][si] = __builtin_amdgcn_mfma_f32_16x16x32_bf16(qf[mf][ki], bb[si], acc[mf][si], 0, 0, 0);
    }
    __builtin_amdgcn_s_setprio(0);
    int shb = (i & 3) * 16 + (lr >> 2);
    float cp[4] = {0.f, 0.f, 0.f, 0.f};
#pragma unroll
    for (int mf = 0; mf < 2; mf++)
#pragma unroll
      for (int i2 = 0; i2 < 4; i2++) {
        uint32_t wlo = (uint32_t)(mwreg[mf * 4 + i2] >> shb);
        float ri = rinv[mf][i2];
#pragma unroll
        for (int si = 0; si < 4; si++)
          cp[si] = fmaf(EXP2(acc[mf][si][i2] + mask_bias(wlo, 4 * si)), ri, cp[si]);
      }
#pragma unroll
    for (int si = 0; si < 4; si++) {
      float v = cp[si];
      v += __shfl_xor(v, 16);
      v += __shfl_xor(v, 32);
      if (lc == 0) atomicAdd(&colacc[i * 64 + si * 16 + lr], v);
    }
    SBAR();
    cur ^= 1;
  }
  __syncthreads();
  if (t < 512) atomicAdd(&abG[t], colacc[t]);
}

// ---- xbar[h*4+b][d] = sum_s abar[h,b,s] * x[b,s,d] -------------------------
__global__ void k_xbar(const float* __restrict__ x, const float* __restrict__ abar,
                       float* __restrict__ xbar) {
  __shared__ float ab[8][128];
  int bx = blockIdx.x;            // dc(4) * 16 + sc(16)
  int b = blockIdx.y;
  int dc = bx >> 4, sc = bx & 15;
  int t = threadIdx.x;
  int d = dc * 256 + t;
  int sc0 = sc * 128;
  for (int i = t; i < 1024; i += 256) {
    int hh = i >> 7, s = i & 127;
    ab[hh][s] = abar[(hh * 4 + b) * 2048 + sc0 + s];
  }
  __syncthreads();
  float acc[8] = {0,0,0,0,0,0,0,0};
  const float* xp = x + ((long)b * 2048 + sc0) * 1024 + d;
  for (int s = 0; s < 128; s++) {
    float xv = xp[(long)s * 1024];
#pragma unroll
    for (int hh = 0; hh < 8; hh++) acc[hh] += xv * ab[hh][s];
  }
#pragma unroll
  for (int hh = 0; hh < 8; hh++) atomicAdd(&xbar[(hh * 4 + b) * 1024 + d], acc[hh]);
}

// ---- ocat[b][h*128+k] += xbar[h,b,dc*128..+128) @ Wv[h][dc*128..+128)[k] ----
__global__ void k_ov(const float* __restrict__ Wv, const float* __restrict__ xbar,
                     float* __restrict__ ocat) {
  __shared__ float xb[128];
  int hb = blockIdx.x, dc = blockIdx.y;
  int h = hb >> 2, b = hb & 3;
  int k = threadIdx.x;   // 128
  xb[k] = xbar[hb * 1024 + dc * 128 + k];
  __syncthreads();
  float acc = 0.f;
  const float* wp = Wv + (long)h * 131072 + (long)(dc * 128) * 128 + k;
#pragma unroll 8
  for (int d = 0; d < 128; d++) acc += xb[d] * wp[(long)d * 128];
  atomicAdd(&ocat[b * 1024 + h * 128 + k], acc);
}

// ---- out1[b][d] = ocat[b,:] . W_lin[d,:] + b_lin[d] -------------------------
__global__ void k_lin(const float* __restrict__ ocat, const float* __restrict__ Wlin,
                      const float* __restrict__ blin, float* __restrict__ out1) {
  int gw = blockIdx.x * 4 + (threadIdx.x >> 6);   // 0..4095 = b*1024+d
  int l = threadIdx.x & 63;
  int b = gw >> 10, d = gw & 1023;
  const float* o = ocat + b * 1024;
  const float* wr = Wlin + (long)d * 1024;
  float acc = 0.f;
  for (int f = l; f < 1024; f += 64) acc += o[f] * wr[f];
#pragma unroll
  for (int m = 32; m; m >>= 1) acc += __shfl_xor(acc, m);
  if (l == 0) out1[gw] = acc + blin[d];
}

// ---- out[b][c] = out1[b,:] . W_last[c,:] + b_last[c] ------------------------
__global__ void k_last(const float* __restrict__ out1, const float* __restrict__ Wlast,
                       const float* __restrict__ blast, float* __restrict__ out) {
  int gw = blockIdx.x * 4 + (threadIdx.x >> 6);   // 0..511 = b*128+c
  int l = threadIdx.x & 63;
  int b = gw >> 7, c = gw & 127;
  const float* i1 = out1 + b * 1024;
  const float* wr = Wlast + (long)c * 1024;
  float acc = 0.f;
  for (int f = l; f < 1024; f += 64) acc += i1[f] * wr[f];
#pragma unroll
  for (int m = 32; m; m >>= 1) acc += __shfl_xor(acc, m);
  if (l == 0) out[gw] = acc + blast[c];
}

extern "C" void kernel_launch(void* const* d_in, const int* in_sizes, int n_in,
                              void* d_out, int out_size, void* d_ws, size_t ws_size,
                              hipStream_t stream) {
  const float* x     = (const float*)d_in[0];
  const void*  mask  = d_in[1];
  const float* Wq    = (const float*)d_in[2];
  const float* Wk    = (const float*)d_in[3];
  const float* Wv    = (const float*)d_in[4];
  const float* Wlin  = (const float*)d_in[5];
  const float* blin  = (const float*)d_in[6];
  const float* Wlast = (const float*)d_in[7];
  const float* blast = (const float*)d_in[8];
  float* out = (float*)d_out;

  char* ws = (char*)d_ws;
  // ws layout (bytes)
  const size_t OFF_FLAG = 0;                      // 256
  const size_t OFF_BITS = 256;                    // 2,097,152
  const size_t OFF_XBF  = 2097408;                // 16,777,216
  const size_t OFF_WQKT = 18874624;               // 4,194,304
  const size_t OFF_QK   = 23068928;               // 33,554,432
  const size_t OFF_ABAR = 56623360;               // 262,144
  const size_t OFF_XBAR = 56885504;               // 131,072
  const size_t OFF_RSUM = 57016576;               // 262,144
  const size_t OFF_OCAT = 57278720;               // 16,384
  const size_t OFF_OUT1 = 57295104;               // 16,384

  int* flag = (int*)(ws + OFF_FLAG);
  unsigned long long* bits = (unsigned long long*)(ws + OFF_BITS);
  unsigned short* xbf  = (unsigned short*)(ws + OFF_XBF);
  unsigned short* wqkt = (unsigned short*)(ws + OFF_WQKT);
  unsigned short* qkb  = (unsigned short*)(ws + OFF_QK);
  float* abar = (float*)(ws + OFF_ABAR);
  float* xbarp = (float*)(ws + OFF_XBAR);
  float* rsum = (float*)(ws + OFF_RSUM);
  float* ocat = (float*)(ws + OFF_OCAT);
  float* out1 = (float*)(ws + OFF_OUT1);

  // zero abar + xbar + rowsum + ocat (contiguous)
  hipMemsetAsync(ws + OFF_ABAR, 0, 262144 + 131072 + 262144 + 16384, stream);
  k_cvt_x<<<8192, 256, 0, stream>>>((const float4*)x, (uint2*)xbf, (const uint32_t*)mask, flag);
  k_bitpack<<<16384, 256, 0, stream>>>(mask, flag, bits);
  k_cvt_w<<<8192, 256, 0, stream>>>(Wq, Wk, wqkt);
  k_gemm256<<<256, 512, 0, stream>>>(xbf, wqkt, qkb);
  k_attn_rs<<<1024, 512, 0, stream>>>(qkb, bits, rsum);
  k_attn_cs<<<1024, 512, 0, stream>>>(qkb, bits, rsum, abar);
  k_xbar<<<dim3(64, 4), 256, 0, stream>>>(x, abar, xbarp);
  k_ov<<<dim3(32, 8), 128, 0, stream>>>(Wv, xbarp, ocat);
  k_lin<<<1024, 256, 0, stream>>>(ocat, Wlin, blin, out1);
  k_last<<<128, 256, 0, stream>>>(out1, Wlast, blast, out);
}